// Round 16
// baseline (61.824 us; speedup 1.0000x reference)
//
#include <hip/hip_runtime.h>
#include <hip/hip_bf16.h>
#include <math.h>

#define M 4096
#define ALPHA 0.2f
#define L2E 1.4426950408889634f
#define PACK_BLOCKS 2048                    // x8 grid-stride int4 each
#define PRED_BLOCKS 2048                    // x8 float4 stores each

typedef __attribute__((ext_vector_type(8))) short bf16x8_t;
typedef __attribute__((ext_vector_type(4))) float f32x4_t;

#define EXP2F(x) __builtin_amdgcn_exp2f(x)

__device__ inline unsigned short f2bf(float f) {      // RNE (cold)
    unsigned int u = __float_as_uint(f);
    u = (u + 0x7fffu + ((u >> 16) & 1u)) >> 16;
    return (unsigned short)u;
}
__device__ inline unsigned short f2bf_fast(float f) { // round-half-up (hot, p>=0)
    return (unsigned short)((__float_as_uint(f) + 0x8000u) >> 16);
}
__device__ inline size_t whb_idx(int i, int c, int NFB) {
    return (((size_t)(i >> 5) * NFB + (c >> 4)) * 64 +
            (((i & 31) >> 3) * 16 + (c & 15))) * 8 + (i & 7);
}

// ========== K1 (fat): pack adj -> packedT (grid-stride x8) || Wh1/WhB1/si1/sk1 ==========
__global__ __launch_bounds__(256) void prep_fat_kernel(const int* __restrict__ adj,
                                                       unsigned int* __restrict__ packedT,
                                                       const float* __restrict__ h0,
                                                       const float* __restrict__ W1,
                                                       const float* __restrict__ a1,
                                                       unsigned short* __restrict__ WhB1,
                                                       float* __restrict__ si1,
                                                       float* __restrict__ sk1) {
    int lane = threadIdx.x & 63;
    if (blockIdx.x < PACK_BLOCKS) {
        int gid = blockIdx.x * 256 + threadIdx.x;
#pragma unroll
        for (int t = 0; t < 8; t++) {
            int g = gid + t * (PACK_BLOCKS * 256);     // int4 index over M*M/4
            int4 av = ((const int4*)adj)[g];
            unsigned int nib = (av.x > 0 ? 1u : 0u) | (av.y > 0 ? 2u : 0u) |
                               (av.z > 0 ? 4u : 0u) | (av.w > 0 ? 8u : 0u);
            unsigned int sh = nib << ((lane & 7) * 4);
            sh |= __shfl_xor(sh, 1);
            sh |= __shfl_xor(sh, 2);
            sh |= __shfl_xor(sh, 4);
            if ((lane & 7) == 0) packedT[(size_t)((g >> 3) & 127) * M + (g >> 10)] = sh;
        }
        return;
    }
    int wave = threadIdx.x >> 6;
    int i = (blockIdx.x - PACK_BLOCKS) * 4 + wave;
    float acc = 0.f;                                   // Wh1[i][lane]
#pragma unroll
    for (int j = 0; j < 64; j++)
        acc += h0[(size_t)i * 64 + j] * W1[j * 64 + lane];
    float vi = acc * a1[lane], vk = acc * a1[64 + lane];
#pragma unroll
    for (int off = 32; off; off >>= 1) { vi += __shfl_xor(vi, off); vk += __shfl_xor(vk, off); }
    if (lane == 0) { si1[i] = vi; sk1[i] = vk; }
    WhB1[whb_idx(i, lane, 4)] = f2bf(acc);
}

// ========== K2/K3: full-K fused attention, 512 thr (8 waves, K/8 each), 8 rows/block =====
// 512 blocks = 2 blocks/CU (prologue of one hides under compute of the other).
// FINAL=false (F=64): epilogue = normalize+ELU -> h1 -> Wh2=h1@W2 -> WhB2/si2/sk2.
// FINAL=true  (F=32): epilogue = normalize+ELU -> hL write + omega dots -> p_i/p_k.
template <int F, bool FINAL>
__global__ __launch_bounds__(512) void attn_fused_kernel(
    const unsigned short* __restrict__ WhB,
    const float* __restrict__ s_i, const float* __restrict__ s_k,
    const unsigned int* __restrict__ packedT,
    const float* __restrict__ W2, const float* __restrict__ a2,
    unsigned short* __restrict__ WhB2, float* __restrict__ si2, float* __restrict__ sk2,
    const float* __restrict__ omega, float* __restrict__ hL_out,
    float* __restrict__ p_i, float* __restrict__ p_k) {
    constexpr int NFB = F / 16;
    constexpr int NWAVE = 8;
    constexpr int WPW = (M / 32) / NWAVE;              // words per wave = 16
    __shared__ unsigned int mask_lds[8][129];          // 8 rows x 128 words (+pad) 4.1 KB
    __shared__ float acc_lds[NWAVE][8][F + 4];         // F+4 pad -> max 2-way (free, m136)
    __shared__ float sred[NWAVE][8];
    __shared__ float wred[NWAVE];
    __shared__ float h_lds[8][F + 1];

    int tid = threadIdx.x, wave = tid >> 6, lane = tid & 63;
    int R0 = blockIdx.x * 8;

    // deterministic global skmax (identical in every block)
    float m = -INFINITY;
#pragma unroll
    for (int t = 0; t < M / 512; t++) m = fmaxf(m, s_k[tid + t * 512]);
#pragma unroll
    for (int off = 32; off; off >>= 1) m = fmaxf(m, __shfl_xor(m, off));
    if (lane == 0) wred[wave] = m;
    // stage mask tile: 8 rows x 128 words (r fastest -> contiguous in packedT)
#pragma unroll
    for (int q = 0; q < 2; q++) {
        int lin = q * 512 + tid;
        int st = lin >> 3, r = lin & 7;
        mask_lds[r][st] = packedT[(size_t)st * M + R0 + r];
    }
    __syncthreads();
    float skmax = wred[0];
#pragma unroll
    for (int w = 1; w < NWAVE; w++) skmax = fmaxf(skmax, wred[w]);

    int fl = lane & 15, kg = lane >> 4;
    int row = R0 + (fl & 7);                           // 8 rows; fl 8..15 mirror 0..7
    float si = s_i[row];
    float xm = si + skmax;
    float rl2 = fmaxf(xm, ALPHA * xm) * L2E;
    f32x4_t acc[NFB];
#pragma unroll
    for (int fb = 0; fb < NFB; fb++) acc[fb] = (f32x4_t)0.f;
    float rsum = 0.f;
    const int kw0 = wave * WPW;
#pragma unroll 4
    for (int st = 0; st < WPW; st++) {
        int kb = (kw0 + st) * 32;
        float4 sa = *(const float4*)&s_k[kb + kg * 8];
        float4 sb = *(const float4*)&s_k[kb + kg * 8 + 4];
        unsigned int word = mask_lds[fl & 7][kw0 + st];
        float sv[8] = { sa.x, sa.y, sa.z, sa.w, sb.x, sb.y, sb.z, sb.w };
        union { bf16x8_t v; unsigned short u[8]; } af;
#pragma unroll
        for (int j = 0; j < 8; j++) {
            float x = si + sv[j];
            float e = fmaxf(x, ALPHA * x);             // leakyrelu
            float p = EXP2F(fmaf(e, L2E, -rl2));       // unnormalized weight <= 1
            p = ((word >> (kg * 8 + j)) & 1u) ? p : 0.f;
            rsum += p;
            af.u[j] = f2bf_fast(p);
        }
        const unsigned short* bp = WhB + (size_t)(kw0 + st) * (NFB * 512) + (size_t)lane * 8;
#pragma unroll
        for (int fb = 0; fb < NFB; fb++) {
            bf16x8_t bfrag = *(const bf16x8_t*)(bp + (size_t)fb * 512);
            acc[fb] = __builtin_amdgcn_mfma_f32_16x16x32_bf16(af.v, bfrag, acc[fb], 0, 0, 0);
        }
    }
    // rsum: lanes {l, l+16, l+32, l+48} partial; rows fl and fl+8 both computed row fl&7
    rsum += __shfl_xor(rsum, 16);
    rsum += __shfl_xor(rsum, 32);
    rsum += __shfl_xor(rsum, 8);                       // merge fl / fl+8 duplicates... 
    // NOTE: rows are duplicated across fl and fl+8 (A-fragment rows 8..15 = rows 0..7 of
    // the 8-row block? NO — see below: we use 16-row MFMA tiles with rows 8..15 zero-padded)
    if (lane < 8) sred[wave][lane] = rsum;
    // spill acc (D layout: col=fl, row=kg*4+r) -- only cols 0..7 are real rows
#pragma unroll
    for (int fb = 0; fb < NFB; fb++)
#pragma unroll
        for (int r = 0; r < 4; r++)
            if (fl < 8) acc_lds[wave][fl][fb * 16 + kg * 4 + r] = 0.f;  // placeholder
    __syncthreads();
    // ---- THIS VERSION IS WRONG -- see corrected kernel below ----
}

// The 8-row variant above is incorrect (16x16 MFMA needs 16 A-rows). Use 16 rows/block
// with 512 threads: 8 waves, each wave covers K/8 = 512 (WPW=16), rows = 16.
template <int F, bool FINAL>
__global__ __launch_bounds__(512) void attn_fused16_kernel(
    const unsigned short* __restrict__ WhB,
    const float* __restrict__ s_i, const float* __restrict__ s_k,
    const unsigned int* __restrict__ packedT,
    const float* __restrict__ W2, const float* __restrict__ a2,
    unsigned short* __restrict__ WhB2, float* __restrict__ si2, float* __restrict__ sk2,
    const float* __restrict__ omega, float* __restrict__ hL_out,
    float* __restrict__ p_i, float* __restrict__ p_k) {
    constexpr int NFB = F / 16;
    constexpr int NWAVE = 8;
    constexpr int WPW = (M / 32) / NWAVE;              // 16 words per wave
    __shared__ unsigned int mask_lds[16][129];         // 8.25 KB
    __shared__ float acc_lds[NWAVE][16][F + 4];        // 34.8 / 18.4 KB
    __shared__ float sred[NWAVE][16];
    __shared__ float wred[NWAVE];
    __shared__ float h_lds[16][F + 1];

    int tid = threadIdx.x, wave = tid >> 6, lane = tid & 63;
    int R0 = blockIdx.x * 16;

    float m = -INFINITY;
#pragma unroll
    for (int t = 0; t < M / 512; t++) m = fmaxf(m, s_k[tid + t * 512]);
#pragma unroll
    for (int off = 32; off; off >>= 1) m = fmaxf(m, __shfl_xor(m, off));
    if (lane == 0) wred[wave] = m;
#pragma unroll
    for (int q = 0; q < 4; q++) {                      // 16 rows x 128 words
        int lin = q * 512 + tid;
        int st = lin >> 4, r = lin & 15;
        mask_lds[r][st] = packedT[(size_t)st * M + R0 + r];
    }
    __syncthreads();
    float skmax = wred[0];
#pragma unroll
    for (int w = 1; w < NWAVE; w++) skmax = fmaxf(skmax, wred[w]);

    int fl = lane & 15, kg = lane >> 4;
    int row = R0 + fl;
    float si = s_i[row];
    float xm = si + skmax;
    float rl2 = fmaxf(xm, ALPHA * xm) * L2E;
    f32x4_t acc[NFB];
#pragma unroll
    for (int fb = 0; fb < NFB; fb++) acc[fb] = (f32x4_t)0.f;
    float rsum = 0.f;
    const int kw0 = wave * WPW;
#pragma unroll 4
    for (int st = 0; st < WPW; st++) {
        int kb = (kw0 + st) * 32;
        float4 sa = *(const float4*)&s_k[kb + kg * 8];
        float4 sb = *(const float4*)&s_k[kb + kg * 8 + 4];
        unsigned int word = mask_lds[fl][kw0 + st];
        float sv[8] = { sa.x, sa.y, sa.z, sa.w, sb.x, sb.y, sb.z, sb.w };
        union { bf16x8_t v; unsigned short u[8]; } af;
#pragma unroll
        for (int j = 0; j < 8; j++) {
            float x = si + sv[j];
            float e = fmaxf(x, ALPHA * x);
            float p = EXP2F(fmaf(e, L2E, -rl2));
            p = ((word >> (kg * 8 + j)) & 1u) ? p : 0.f;
            rsum += p;
            af.u[j] = f2bf_fast(p);
        }
        const unsigned short* bp = WhB + (size_t)(kw0 + st) * (NFB * 512) + (size_t)lane * 8;
#pragma unroll
        for (int fb = 0; fb < NFB; fb++) {
            bf16x8_t bfrag = *(const bf16x8_t*)(bp + (size_t)fb * 512);
            acc[fb] = __builtin_amdgcn_mfma_f32_16x16x32_bf16(af.v, bfrag, acc[fb], 0, 0, 0);
        }
    }
    rsum += __shfl_xor(rsum, 16);
    rsum += __shfl_xor(rsum, 32);
    if (lane < 16) sred[wave][lane] = rsum;
#pragma unroll
    for (int fb = 0; fb < NFB; fb++)
#pragma unroll
        for (int r = 0; r < 4; r++)
            acc_lds[wave][kg * 4 + r][fb * 16 + fl] = acc[fb][r];
    __syncthreads();

    // cross-wave reduce + normalize + ELU -> h_lds
#pragma unroll
    for (int q = 0; q < (16 * F + 511) / 512; q++) {
        int cell = q * 512 + tid;
        if (cell < 16 * F) {
            int r = cell / F, c = cell % F;
            float s = 0.f, S = 0.f;
#pragma unroll
            for (int w = 0; w < NWAVE; w++) { s += acc_lds[w][r][c]; S += sred[w][r]; }
            float h = S > 0.f ? s / S : 0.f;
            h = h > 0.f ? h : (__expf(h) - 1.f);
            h_lds[r][c] = h;
            if (FINAL) hL_out[(size_t)(R0 + r) * F + c] = h;
        }
    }
    __syncthreads();

    // epilogue on 16 complete rows (threads 0..511: r = t>>5, c = t&31)
    {
        int r = tid >> 5, c = tid & 31;
        float vi, vk;
        if (!FINAL) {
            float w2 = 0.f;                            // Wh2[r][c] = h1[r] . W2[:,c]
#pragma unroll
            for (int f = 0; f < 64; f++) w2 += h_lds[r][f] * W2[f * 32 + c];
            WhB2[whb_idx(R0 + r, c, 2)] = f2bf(w2);
            vi = w2 * a2[c];
            vk = w2 * a2[32 + c];
        } else {
            float hv = h_lds[r][c];
            vi = hv * omega[c];
            vk = hv * omega[32 + c];
        }
#pragma unroll
        for (int off = 16; off; off >>= 1) { vi += __shfl_xor(vi, off); vk += __shfl_xor(vk, off); }
        if ((tid & 31) == 0) {
            if (!FINAL) { si2[R0 + r] = vi; sk2[R0 + r] = vk; }
            else        { p_i[R0 + r] = vi; p_k[R0 + r] = vk; }
        }
    }
}

// ================= K4: pairwise sigmoid (grid-stride x8) =================
__global__ __launch_bounds__(256) void pred_kernel(const float* __restrict__ p_i,
                                                   const float* __restrict__ p_k,
                                                   float* __restrict__ out) {
    int gid = blockIdx.x * 256 + threadIdx.x;
#pragma unroll
    for (int t = 0; t < 8; t++) {
        int idx4 = gid + t * (PRED_BLOCKS * 256);
        int i = idx4 >> 10;
        int k4 = (idx4 & 1023) * 4;
        float pi = p_i[i];
        float4 pk = *(const float4*)&p_k[k4];
        float4 o;
        o.x = 1.f / (1.f + __expf(-(pi + pk.x)));
        o.y = 1.f / (1.f + __expf(-(pi + pk.y)));
        o.z = 1.f / (1.f + __expf(-(pi + pk.z)));
        o.w = 1.f / (1.f + __expf(-(pi + pk.w)));
        *(float4*)&out[(size_t)i * M + k4] = o;
    }
}

extern "C" void kernel_launch(void* const* d_in, const int* in_sizes, int n_in,
                              void* d_out, int out_size, void* d_ws, size_t ws_size,
                              hipStream_t stream) {
    const float* h0    = (const float*)d_in[0];
    const int*   adj   = (const int*)d_in[1];
    const float* W1    = (const float*)d_in[2];
    const float* a1    = (const float*)d_in[3];
    const float* W2    = (const float*)d_in[4];
    const float* a2    = (const float*)d_in[5];
    const float* omega = (const float*)d_in[6];
    float* out = (float*)d_out;

    char* ws = (char*)d_ws;
    unsigned int*   packedT = (unsigned int*)(ws + 0);         // 2 MB
    unsigned short* WhB1    = (unsigned short*)(ws + 2097152); // 512 KB
    unsigned short* WhB2    = (unsigned short*)(ws + 2621440); // 256 KB
    float* si1 = (float*)(ws + 2883584);
    float* sk1 = (float*)(ws + 2899968);
    float* si2 = (float*)(ws + 2916352);
    float* sk2 = (float*)(ws + 2932736);
    float* pi  = (float*)(ws + 2949120);
    float* pk  = (float*)(ws + 2965504);

    // K1: pack (2048 blocks, x8 stride) || layer-1 GEMM/svec (1024 blocks)
    prep_fat_kernel<<<PACK_BLOCKS + M / 4, 256, 0, stream>>>(
        adj, packedT, h0, W1, a1, WhB1, si1, sk1);

    // K2: layer-1 full-K attention + mid epilogue (256 blocks x 512 thr, 8 waves)
    attn_fused16_kernel<64, false><<<M / 16, 512, 0, stream>>>(
        WhB1, si1, sk1, packedT, W2, a2, WhB2, si2, sk2,
        nullptr, nullptr, nullptr, nullptr);

    // K3: layer-2 full-K attention + out epilogue (-> hL tail, pi, pk)
    attn_fused16_kernel<32, true><<<M / 16, 512, 0, stream>>>(
        WhB2, si2, sk2, packedT, nullptr, nullptr, nullptr, nullptr, nullptr,
        omega, out + (size_t)M * M, pi, pk);

    // K4: pairwise sigmoid
    pred_kernel<<<PRED_BLOCKS, 256, 0, stream>>>(pi, pk, out);
}

// Round 18
// 55.918 us; speedup vs baseline: 1.1056x; 1.1056x over previous
//
#include <hip/hip_runtime.h>
#include <hip/hip_bf16.h>
#include <math.h>

#define M 4096
#define ALPHA 0.2f
#define L2E 1.4426950408889634f

typedef __attribute__((ext_vector_type(8))) short bf16x8_t;
typedef __attribute__((ext_vector_type(4))) float f32x4_t;

#define EXP2F(x) __builtin_amdgcn_exp2f(x)

__device__ inline unsigned short f2bf(float f) {      // RNE (cold)
    unsigned int u = __float_as_uint(f);
    u = (u + 0x7fffu + ((u >> 16) & 1u)) >> 16;
    return (unsigned short)u;
}
__device__ inline unsigned short f2bf_fast(float f) { // round-half-up (hot, p>=0)
    return (unsigned short)((__float_as_uint(f) + 0x8000u) >> 16);
}
__device__ inline size_t whb_idx(int i, int c, int NFB) {
    return (((size_t)(i >> 5) * NFB + (c >> 4)) * 64 +
            (((i & 31) >> 3) * 16 + (c & 15))) * 8 + (i & 7);
}

// ========== K1: Wh1 = h0@W1 (regs) -> WhB1 frag scatter + si1/sk1 (1024 blocks) ==========
__global__ __launch_bounds__(256) void fused_in_kernel(const float* __restrict__ h0,
                                                       const float* __restrict__ W1,
                                                       const float* __restrict__ a1,
                                                       unsigned short* __restrict__ WhB1,
                                                       float* __restrict__ si1,
                                                       float* __restrict__ sk1) {
    int wave = threadIdx.x >> 6, lane = threadIdx.x & 63;
    int i = blockIdx.x * 4 + wave;
    float acc = 0.f;                                   // Wh1[i][lane]
#pragma unroll
    for (int j = 0; j < 64; j++)
        acc += h0[(size_t)i * 64 + j] * W1[j * 64 + lane];
    float vi = acc * a1[lane], vk = acc * a1[64 + lane];
#pragma unroll
    for (int off = 32; off; off >>= 1) { vi += __shfl_xor(vi, off); vk += __shfl_xor(vk, off); }
    if (lane == 0) { si1[i] = vi; sk1[i] = vk; }
    WhB1[whb_idx(i, lane, 4)] = f2bf(acc);
}

// ====== K2/K3: full-K fused attention, 1024 thr (16 waves, K/16 = 256 per wave) ======
// PACK=true  (K2): each wave burst-loads its OWN 16rows x 256cols adj slice, packs to
//                  per-wave LDS (no cross-wave sync), writes packedT for K3.
// PACK=false (K3): stages packedT tile into mask_lds (R15 path).
// FINAL=false (F=64): epilogue = norm+ELU -> h1 -> Wh2=h1@W2 -> WhB2/si2/sk2.
// FINAL=true  (F=32): epilogue = norm+ELU -> hL write + omega dots -> p_i/p_k.
template <int F, bool FINAL, bool PACK>
__global__ __launch_bounds__(1024) void attn_fused_kernel(
    const unsigned short* __restrict__ WhB,
    const float* __restrict__ s_i, const float* __restrict__ s_k,
    const int* __restrict__ adj, unsigned int* __restrict__ packedT,
    const float* __restrict__ W2, const float* __restrict__ a2,
    unsigned short* __restrict__ WhB2, float* __restrict__ si2, float* __restrict__ sk2,
    const float* __restrict__ omega, float* __restrict__ hL_out,
    float* __restrict__ p_i, float* __restrict__ p_k) {
    constexpr int NFB = F / 16;
    constexpr int NWAVE = 16;
    constexpr int WPW = (M / 32) / NWAVE;              // 8 words per wave
    __shared__ unsigned int mask_lds[16][129];         // K3 path (8.25 KB)
    __shared__ unsigned int wlds[NWAVE][16][WPW];      // K2 path: per-wave slice (8 KB)
    __shared__ float acc_lds[NWAVE][16][F + 1];        // 66.6 / 33.8 KB
    __shared__ float sred[NWAVE][16];
    __shared__ float wred[NWAVE];
    __shared__ float h_lds[16][F + 1];

    int tid = threadIdx.x, wave = tid >> 6, lane = tid & 63;
    int R0 = blockIdx.x * 16;

    // deterministic global skmax (identical in every block)
    float m = -INFINITY;
#pragma unroll
    for (int t = 0; t < M / 1024; t++) m = fmaxf(m, s_k[tid + t * 1024]);
#pragma unroll
    for (int off = 32; off; off >>= 1) m = fmaxf(m, __shfl_xor(m, off));
    if (lane == 0) wred[wave] = m;

    if (PACK) {
        // per-wave adj slice pack: rows 0..15, cols [wave*256, wave*256+256)
        // 4 bursts x 4 rows; each lane one int4 per row -> independent loads
#pragma unroll
        for (int b = 0; b < 4; b++) {
            int4 av[4];
#pragma unroll
            for (int rr = 0; rr < 4; rr++) {
                int r = b * 4 + rr;
                av[rr] = ((const int4*)adj)[(size_t)(R0 + r) * (M / 4) + wave * 64 + lane];
            }
#pragma unroll
            for (int rr = 0; rr < 4; rr++) {
                int r = b * 4 + rr;
                unsigned int nib = (av[rr].x > 0 ? 1u : 0u) | (av[rr].y > 0 ? 2u : 0u) |
                                   (av[rr].z > 0 ? 4u : 0u) | (av[rr].w > 0 ? 8u : 0u);
                unsigned int sh = nib << ((lane & 7) * 4);
                sh |= __shfl_xor(sh, 1);
                sh |= __shfl_xor(sh, 2);
                sh |= __shfl_xor(sh, 4);
                if ((lane & 7) == 0) wlds[wave][r][lane >> 3] = sh;
            }
        }
    } else {
        // stage mask tile from packedT: 16 rows x 128 words
#pragma unroll
        for (int q = 0; q < 2; q++) {
            int lin = q * 1024 + tid;
            int st = lin >> 4, r = lin & 15;
            mask_lds[r][st] = packedT[(size_t)st * M + R0 + r];
        }
    }
    __syncthreads();
    float skmax = wred[0];
#pragma unroll
    for (int w = 1; w < NWAVE; w++) skmax = fmaxf(skmax, wred[w]);
    if (PACK) {
        // coalesced packedT writeback for K3 (fire-and-forget, overlaps compute)
#pragma unroll
        for (int q = 0; q < 2; q++) {
            int lin = q * 1024 + tid;
            int kw = lin >> 4, r = lin & 15;
            packedT[(size_t)kw * M + R0 + r] = wlds[kw >> 3][r][kw & 7];
        }
    }

    int fl = lane & 15, kg = lane >> 4;
    int row = R0 + fl;
    float si = s_i[row];
    float xm = si + skmax;
    float rl2 = fmaxf(xm, ALPHA * xm) * L2E;
    f32x4_t acc[NFB];
#pragma unroll
    for (int fb = 0; fb < NFB; fb++) acc[fb] = (f32x4_t)0.f;
    float rsum = 0.f;
    const int kw0 = wave * WPW;
#pragma unroll
    for (int st = 0; st < WPW; st++) {
        int kb = (kw0 + st) * 32;
        float4 sa = *(const float4*)&s_k[kb + kg * 8];
        float4 sb = *(const float4*)&s_k[kb + kg * 8 + 4];
        unsigned int word = PACK ? wlds[wave][fl][st] : mask_lds[fl][kw0 + st];
        float sv[8] = { sa.x, sa.y, sa.z, sa.w, sb.x, sb.y, sb.z, sb.w };
        union { bf16x8_t v; unsigned short u[8]; } af;
#pragma unroll
        for (int j = 0; j < 8; j++) {
            float x = si + sv[j];
            float e = fmaxf(x, ALPHA * x);             // leakyrelu
            float p = EXP2F(fmaf(e, L2E, -rl2));       // unnormalized weight <= 1
            p = ((word >> (kg * 8 + j)) & 1u) ? p : 0.f;
            rsum += p;
            af.u[j] = f2bf_fast(p);
        }
        const unsigned short* bp = WhB + (size_t)(kw0 + st) * (NFB * 512) + (size_t)lane * 8;
#pragma unroll
        for (int fb = 0; fb < NFB; fb++) {
            bf16x8_t bfrag = *(const bf16x8_t*)(bp + (size_t)fb * 512);
            acc[fb] = __builtin_amdgcn_mfma_f32_16x16x32_bf16(af.v, bfrag, acc[fb], 0, 0, 0);
        }
    }
    rsum += __shfl_xor(rsum, 16);
    rsum += __shfl_xor(rsum, 32);
    if (lane < 16) sred[wave][lane] = rsum;
    // spill acc (D layout: col=fl, row=kg*4+r)
#pragma unroll
    for (int fb = 0; fb < NFB; fb++)
#pragma unroll
        for (int r = 0; r < 4; r++)
            acc_lds[wave][kg * 4 + r][fb * 16 + fl] = acc[fb][r];
    __syncthreads();

    // cross-wave reduce + normalize + ELU -> h_lds (one cell per thread)
    if (tid < 16 * F) {
        int r = tid / F, c = tid % F;
        float s = 0.f, S = 0.f;
#pragma unroll
        for (int w = 0; w < NWAVE; w++) { s += acc_lds[w][r][c]; S += sred[w][r]; }
        float h = S > 0.f ? s / S : 0.f;
        h = h > 0.f ? h : (__expf(h) - 1.f);
        h_lds[r][c] = h;
        if (FINAL) hL_out[(size_t)(R0 + r) * F + c] = h;
    }
    __syncthreads();

    // epilogue on 16 complete rows (threads 0..511: r = t>>5, c = t&31)
    if (tid < 512) {
        int r = tid >> 5, c = tid & 31;
        float vi, vk;
        if (!FINAL) {
            float w2 = 0.f;                            // Wh2[r][c] = h1[r] . W2[:,c]
#pragma unroll
            for (int f = 0; f < 64; f++) w2 += h_lds[r][f] * W2[f * 32 + c];
            WhB2[whb_idx(R0 + r, c, 2)] = f2bf(w2);
            vi = w2 * a2[c];
            vk = w2 * a2[32 + c];
        } else {
            float hv = h_lds[r][c];
            vi = hv * omega[c];
            vk = hv * omega[32 + c];
        }
#pragma unroll
        for (int off = 16; off; off >>= 1) { vi += __shfl_xor(vi, off); vk += __shfl_xor(vk, off); }
        if ((tid & 31) == 0) {
            if (!FINAL) { si2[R0 + r] = vi; sk2[R0 + r] = vk; }
            else        { p_i[R0 + r] = vi; p_k[R0 + r] = vk; }
        }
    }
}

// ================= K4: pairwise sigmoid (grid-stride x4, R15 config) =================
__global__ __launch_bounds__(256) void pred_kernel(const float* __restrict__ p_i,
                                                   const float* __restrict__ p_k,
                                                   float* __restrict__ out) {
    int gid = blockIdx.x * 256 + threadIdx.x;          // 0 .. M*M/16-1
#pragma unroll
    for (int t = 0; t < 4; t++) {
        int idx4 = gid + t * (M * M / 16);
        int i = idx4 >> 10;
        int k4 = (idx4 & 1023) * 4;
        float pi = p_i[i];
        float4 pk = *(const float4*)&p_k[k4];
        float4 o;
        o.x = 1.f / (1.f + __expf(-(pi + pk.x)));
        o.y = 1.f / (1.f + __expf(-(pi + pk.y)));
        o.z = 1.f / (1.f + __expf(-(pi + pk.z)));
        o.w = 1.f / (1.f + __expf(-(pi + pk.w)));
        *(float4*)&out[(size_t)i * M + k4] = o;
    }
}

extern "C" void kernel_launch(void* const* d_in, const int* in_sizes, int n_in,
                              void* d_out, int out_size, void* d_ws, size_t ws_size,
                              hipStream_t stream) {
    const float* h0    = (const float*)d_in[0];
    const int*   adj   = (const int*)d_in[1];
    const float* W1    = (const float*)d_in[2];
    const float* a1    = (const float*)d_in[3];
    const float* W2    = (const float*)d_in[4];
    const float* a2    = (const float*)d_in[5];
    const float* omega = (const float*)d_in[6];
    float* out = (float*)d_out;

    char* ws = (char*)d_ws;
    unsigned int*   packedT = (unsigned int*)(ws + 0);         // 2 MB
    unsigned short* WhB1    = (unsigned short*)(ws + 2097152); // 512 KB
    unsigned short* WhB2    = (unsigned short*)(ws + 2621440); // 256 KB
    float* si1 = (float*)(ws + 2883584);
    float* sk1 = (float*)(ws + 2899968);
    float* si2 = (float*)(ws + 2916352);
    float* sk2 = (float*)(ws + 2932736);
    float* pi  = (float*)(ws + 2949120);
    float* pk  = (float*)(ws + 2965504);

    // K1: layer-1 GEMM/svec only (adj pack moved into K2)
    fused_in_kernel<<<M / 4, 256, 0, stream>>>(h0, W1, a1, WhB1, si1, sk1);

    // K2: layer-1 attention, packs its own adj slices in-wave, emits packedT for K3
    attn_fused_kernel<64, false, true><<<M / 16, 1024, 0, stream>>>(
        WhB1, si1, sk1, adj, packedT, W2, a2, WhB2, si2, sk2,
        nullptr, nullptr, nullptr, nullptr);

    // K3: layer-2 attention (reads packedT) + out epilogue (-> hL tail, pi, pk)
    attn_fused_kernel<32, true, false><<<M / 16, 1024, 0, stream>>>(
        WhB2, si2, sk2, nullptr, packedT, nullptr, nullptr, nullptr, nullptr, nullptr,
        omega, out + (size_t)M * M, pi, pk);

    // K4: pairwise sigmoid
    pred_kernel<<<M * M / 16 / 256, 256, 0, stream>>>(pi, pk, out);
}